// Round 3
// baseline (398.597 us; speedup 1.0000x reference)
//
#include <hip/hip_runtime.h>

typedef unsigned short u16;
typedef __attribute__((ext_vector_type(4))) float f32x4;
typedef __attribute__((ext_vector_type(8))) short s16x8;
typedef __attribute__((ext_vector_type(4))) unsigned short u16x4;

static __device__ __forceinline__ u16 f2bf(float f) {
    unsigned int x = __float_as_uint(f);
    x += 0x7fffu + ((x >> 16) & 1u);           // round-to-nearest-even
    return (u16)(x >> 16);
}

// ---------------- Stage 1: pooled[b][c] = mean_{h,w} x[b,c,h,w] -------------
// grid 8192 (= B*C), block 256
__global__ __launch_bounds__(256) void pool_kernel(const float* __restrict__ x,
                                                   float* __restrict__ pooled) {
    int bc = blockIdx.x;
    const float* p = x + (size_t)bc * 3136;
    float s = 0.f;
    for (int i = threadIdx.x; i < 784; i += 256) {       // 784*4 = 3136
        f32x4 v = *(const f32x4*)(p + i * 4);
        s += v.x + v.y + v.z + v.w;
    }
#pragma unroll
    for (int off = 32; off; off >>= 1) s += __shfl_xor(s, off);
    __shared__ float red[4];
    int lane = threadIdx.x & 63, wave = threadIdx.x >> 6;
    if (lane == 0) red[wave] = s;
    __syncthreads();
    if (threadIdx.x == 0)
        pooled[bc] = (red[0] + red[1] + red[2] + red[3]) * (1.0f / 3136.0f);
}

// ---------------- Stage 2: h[b][i] = relu(sum_j pooled[b][j]*fc1_w[i][j]) ---
__global__ __launch_bounds__(256) void fc1_kernel(const float* __restrict__ pooled,
                                                  const float* __restrict__ w,
                                                  float* __restrict__ h) {
    __shared__ float pv[256];
    int b = blockIdx.x >> 6;
    pv[threadIdx.x] = pooled[b * 256 + threadIdx.x];
    __syncthreads();
    int lane = threadIdx.x & 63, wave = threadIdx.x >> 6;
    int i = ((blockIdx.x & 63) << 2) + wave;
    f32x4 v = *(const f32x4*)(w + i * 256 + lane * 4);
    float s = v.x * pv[lane * 4 + 0] + v.y * pv[lane * 4 + 1] +
              v.z * pv[lane * 4 + 2] + v.w * pv[lane * 4 + 3];
#pragma unroll
    for (int off = 32; off; off >>= 1) s += __shfl_xor(s, off);
    if (lane == 0) h[b * 256 + i] = fmaxf(s, 0.f);
}

// ---------------- Stage 3: kern[b][oc] = sum_j h[b][j]*fc2_w[oc][j] + b -----
__global__ __launch_bounds__(256) void fc2_kernel(const float* __restrict__ h,
                                                  const float* __restrict__ w,
                                                  const float* __restrict__ bias,
                                                  float* __restrict__ kern) {
    __shared__ float hv[256];
    int b = blockIdx.x >> 8;
    hv[threadIdx.x] = h[b * 256 + threadIdx.x];
    __syncthreads();
    int lane = threadIdx.x & 63, wave = threadIdx.x >> 6;
    int i = ((blockIdx.x & 255) << 2) + wave;
    f32x4 v = *(const f32x4*)(w + i * 256 + lane * 4);
    float s = v.x * hv[lane * 4 + 0] + v.y * hv[lane * 4 + 1] +
              v.z * hv[lane * 4 + 2] + v.w * hv[lane * 4 + 3];
#pragma unroll
    for (int off = 32; off; off >>= 1) s += __shfl_xor(s, off);
    if (lane == 0) kern[b * 1024 + i] = s + bias[i];
}

// ---------------- Stage 4: dynw[b][o][p][c] = bf16(sigmoid(cw)*weight) -----
// cw[b,o,c,p] = sum_t kern[b, c*4+t] * cog[o, t, p]
__global__ __launch_bounds__(256) void dynw_kernel(const float* __restrict__ kern,
                                                   const float* __restrict__ cogw,
                                                   const float* __restrict__ wgt,
                                                   u16* __restrict__ dynw) {
    __shared__ float wl[2304];                  // wgt[o][256 c][9 p]
    const int o = blockIdx.x & 255;
    const int bg = blockIdx.x >> 8;             // 0..3 -> 8 batches each
    const int c = threadIdx.x;
    const float* wo = wgt + (size_t)o * 2304;
#pragma unroll
    for (int j = 0; j < 9; ++j)                 // fully coalesced
        wl[j * 256 + c] = wo[j * 256 + c];
    __syncthreads();

    float cg0[9], cg1[9], cg2[9], cg3[9];       // cog[o][t][p] — wave-uniform
#pragma unroll
    for (int p = 0; p < 9; ++p) {
        cg0[p] = cogw[(o * 4 + 0) * 9 + p];
        cg1[p] = cogw[(o * 4 + 1) * 9 + p];
        cg2[p] = cogw[(o * 4 + 2) * 9 + p];
        cg3[p] = cogw[(o * 4 + 3) * 9 + p];
    }
    float w9[9];                                // stride-9 LDS read: odd -> conflict-free
#pragma unroll
    for (int p = 0; p < 9; ++p) w9[p] = wl[c * 9 + p];

    for (int b = bg * 8; b < bg * 8 + 8; ++b) {
        f32x4 k4 = *(const f32x4*)(kern + b * 1024 + c * 4);
        u16* dst = dynw + (size_t)(b * 256 + o) * 9 * 256 + c;
#pragma unroll
        for (int p = 0; p < 9; ++p) {
            float cw = k4.x * cg0[p] + k4.y * cg1[p] + k4.z * cg2[p] + k4.w * cg3[p];
            float sg = 1.0f / (1.0f + __expf(-cw));
            dst[p * 256] = f2bf(sg * w9[p]);    // coalesced per (b,p)
        }
    }
}

// ---------------- Stage 5: per-sample conv via implicit GEMM + MFMA --------
// Block tile: 256 o x 112 s (2 output rows). 4 waves; wave = 64 o x 112 s.
// v2 changes vs previous best:
//  * cg-XOR LDS swizzle: cell cg' = cg ^ (((col>>3)&3)<<1). Kills the 7-way
//    bank conflict on staging ds_write_b64 (col stride 20 banks, 8*20%32==0).
//    Read side: same permutation = (quad ^ g(col'))<<3, pair-preserving so
//    ds_read_b128 stays 16B-aligned and k-order inside the frag is unchanged.
//  * Double-buffered LDS + pipelined staging: ONE barrier per cc. Staging for
//    chunk cc+1 is interleaved into the 9 tap-phases of chunk cc: loads issue
//    at phase p (p<7), vmcnt-wait+convert+write land at phase p+2 into the
//    other buffer. Global latency hides under ~2 phases of MFMA.
#define LDSW 40
__global__ __launch_bounds__(256, 2) void conv_kernel(const float* __restrict__ x,
                                                      const u16* __restrict__ dynw,
                                                      float* __restrict__ out) {
    __shared__ u16 lds[2][4 * 58 * LDSW];       // 2 x 18,560 B = 37,120 B
    const int tid = threadIdx.x;
    const int wave = tid >> 6, lane = tid & 63;
    const int l15 = lane & 15, quad = lane >> 4;
    const int gid = blockIdx.x;
    const int slot = gid >> 3;
    const int b = (gid & 7) * 4 + slot / 28;    // same-XCD blocks share b-slabs
    const int stile = slot % 28;
    const int y0 = stile * 2;

    // zero halo columns col=0 and col=57 in BOTH buffers (swizzle-invariant:
    // all 8 cg cells written zero)
    if (tid < 128) {
        int bufi = tid >> 6;
        int t = tid & 63;
        int side = t & 1, yy = (t >> 1) & 3, cg = t >> 3;
        *(u16x4*)&lds[bufi][(yy * 58 + (side ? 57 : 0)) * LDSW + cg * 4] =
            (u16x4){0, 0, 0, 0};
    }

    f32x4 acc[4][7];
#pragma unroll
    for (int mf = 0; mf < 4; ++mf)
#pragma unroll
        for (int nf = 0; nf < 7; ++nf) acc[mf][nf] = (f32x4){0.f, 0.f, 0.f, 0.f};

    // per-nf read bases: rowb = row part (no quad); sw packs the swizzled
    // quad offset ((quad ^ g(xx+dx))<<3) for dx = 0,1,2 (6 bits each)
    int rowb[7], sw[7];
#pragma unroll
    for (int nf = 0; nf < 7; ++nf) {
        int n = nf * 16 + l15;                  // s within the 112-tile
        int r = (n >= 56) ? 1 : 0;
        int xx = n - 56 * r;
        rowb[nf] = (r * 58 + xx) * LDSW;
        int s0 = (quad ^ ((xx >> 3) & 3)) << 3;
        int s1 = (quad ^ (((xx + 1) >> 3) & 3)) << 3;
        int s2 = (quad ^ (((xx + 2) >> 3) & 3)) << 3;
        sw[nf] = s0 | (s1 << 6) | (s2 << 12);
    }
    const u16* Abase = dynw + ((size_t)b * 256 + wave * 64 + l15) * 2304 + quad * 8;
    const float* Xb = x + (size_t)b * 256 * 3136;

    // ---- prologue: stage chunk 0 into buffer 0 (synchronous, swizzled) ----
#pragma unroll
    for (int it = 0; it < 7; ++it) {
        int i = it * 256 + tid;                 // 1792 = 8 cg * 4 yy * 56 xx
        int q = i / 56;
        int xxw = i - q * 56;
        int yy = q & 3;
        int cg = q >> 2;
        int col = xxw + 1;
        int cgx = cg ^ (((col >> 3) & 3) << 1);
        int yg = y0 - 1 + yy;
        u16x4 w = (u16x4){0, 0, 0, 0};
        if ((unsigned)yg < 56u) {
            const float* src = Xb + (size_t)(cg * 4) * 3136 + yg * 56 + xxw;
            w.x = f2bf(src[0]);
            w.y = f2bf(src[3136]);
            w.z = f2bf(src[2 * 3136]);
            w.w = f2bf(src[3 * 3136]);
        }
        *(u16x4*)&lds[0][(yy * 58 + col) * LDSW + cgx * 4] = w;
    }
    __syncthreads();

    // ---- main loop: compute buf[cc&1], pipeline-stage cc+1 into the other --
    for (int cc = 0; cc < 8; ++cc) {
        const u16* Lr = lds[cc & 1];
        u16* Lw = lds[(cc & 1) ^ 1];
        const bool more = (cc < 7);
        float sv[3][4];                         // rotating (unroll-static idx)
        int soff[3];
#pragma unroll
        for (int p = 0; p < 9; ++p) {
            const int dy = p / 3, dx = p % 3;
            s16x8 a0 = *(const s16x8*)(Abase + 0 * 36864 + p * 256 + cc * 32);
            s16x8 a1 = *(const s16x8*)(Abase + 1 * 36864 + p * 256 + cc * 32);
            s16x8 a2 = *(const s16x8*)(Abase + 2 * 36864 + p * 256 + cc * 32);
            s16x8 a3 = *(const s16x8*)(Abase + 3 * 36864 + p * 256 + cc * 32);

            if (more && p < 7) {                // issue staging loads, iter p
                int i = p * 256 + tid;
                int q = i / 56;
                int xxw = i - q * 56;
                int yy = q & 3;
                int cg = q >> 2;
                int col = xxw + 1;
                int cgx = cg ^ (((col >> 3) & 3) << 1);
                soff[p % 3] = (yy * 58 + col) * LDSW + cgx * 4;
                int yg = y0 - 1 + yy;
                float f0 = 0.f, f1 = 0.f, f2 = 0.f, f3 = 0.f;
                if ((unsigned)yg < 56u) {
                    const float* src =
                        Xb + (size_t)((cc + 1) * 32 + cg * 4) * 3136 + yg * 56 + xxw;
                    f0 = src[0];
                    f1 = src[3136];
                    f2 = src[2 * 3136];
                    f3 = src[3 * 3136];
                }
                sv[p % 3][0] = f0; sv[p % 3][1] = f1;
                sv[p % 3][2] = f2; sv[p % 3][3] = f3;
            }

#pragma unroll
            for (int nf = 0; nf < 7; ++nf) {
                int off = rowb[nf] + (dy * 58 + dx) * LDSW + ((sw[nf] >> (6 * dx)) & 63);
                s16x8 bf = *(const s16x8*)(Lr + off);
                acc[0][nf] = __builtin_amdgcn_mfma_f32_16x16x32_bf16(a0, bf, acc[0][nf], 0, 0, 0);
                acc[1][nf] = __builtin_amdgcn_mfma_f32_16x16x32_bf16(a1, bf, acc[1][nf], 0, 0, 0);
                acc[2][nf] = __builtin_amdgcn_mfma_f32_16x16x32_bf16(a2, bf, acc[2][nf], 0, 0, 0);
                acc[3][nf] = __builtin_amdgcn_mfma_f32_16x16x32_bf16(a3, bf, acc[3][nf], 0, 0, 0);
            }

            if (more && p >= 2) {               // convert+write iter p-2
                const int it = p - 2;
                u16x4 wv;
                wv.x = f2bf(sv[it % 3][0]);
                wv.y = f2bf(sv[it % 3][1]);
                wv.z = f2bf(sv[it % 3][2]);
                wv.w = f2bf(sv[it % 3][3]);
                *(u16x4*)(Lw + soff[it % 3]) = wv;
            }
        }
        __syncthreads();
    }

    // epilogue: D[row=quad*4+r][col=l15] (m89/m91-verified C/D layout)
#pragma unroll
    for (int mf = 0; mf < 4; ++mf) {
        int o = wave * 64 + mf * 16 + quad * 4;
        size_t obase = ((size_t)b * 256 + o) * 3136 + (size_t)stile * 112 + l15;
#pragma unroll
        for (int nf = 0; nf < 7; ++nf) {
#pragma unroll
            for (int r = 0; r < 4; ++r)
                out[obase + (size_t)r * 3136 + nf * 16] = acc[mf][nf][r];
        }
    }
}

extern "C" void kernel_launch(void* const* d_in, const int* in_sizes, int n_in,
                              void* d_out, int out_size, void* d_ws, size_t ws_size,
                              hipStream_t stream) {
    const float* x    = (const float*)d_in[0];   // [32,256,56,56] f32
    const float* fc1w = (const float*)d_in[1];   // [256,256]
    const float* fc2w = (const float*)d_in[2];   // [1024,256]
    const float* fc2b = (const float*)d_in[3];   // [1024]
    const float* cogw = (const float*)d_in[4];   // [256,4,3,3]
    const float* wgt  = (const float*)d_in[5];   // [256,256,3,3]
    float* out = (float*)d_out;                  // [32,256,56,56] f32

    char* ws = (char*)d_ws;
    float* pooled = (float*)ws;              // 32 KB
    float* h      = (float*)(ws + 32768);    // 32 KB
    float* kern   = (float*)(ws + 65536);    // 128 KB
    u16*   dynw   = (u16*)(ws + 196608);     // 37.75 MB, [b][o][p][c] bf16

    pool_kernel<<<8192, 256, 0, stream>>>(x, pooled);
    fc1_kernel<<<2048, 256, 0, stream>>>(pooled, fc1w, h);
    fc2_kernel<<<8192, 256, 0, stream>>>(h, fc2w, fc2b, kern);
    dynw_kernel<<<1024, 256, 0, stream>>>(kern, cogw, wgt, dynw);
    conv_kernel<<<896, 256, 0, stream>>>(x, dynw, out);
}

// Round 6
// 368.065 us; speedup vs baseline: 1.0830x; 1.0830x over previous
//
#include <hip/hip_runtime.h>

typedef unsigned short u16;
typedef __attribute__((ext_vector_type(4))) float f32x4;
typedef __attribute__((ext_vector_type(8))) short s16x8;
typedef __attribute__((ext_vector_type(4))) unsigned short u16x4;

static __device__ __forceinline__ u16 f2bf(float f) {
    unsigned int x = __float_as_uint(f);
    x += 0x7fffu + ((x >> 16) & 1u);           // round-to-nearest-even
    return (u16)(x >> 16);
}

// ---------------- Stage 1: pooled[b][c] = mean_{h,w} x[b,c,h,w] -------------
// grid 8192 (= B*C), block 256
__global__ __launch_bounds__(256) void pool_kernel(const float* __restrict__ x,
                                                   float* __restrict__ pooled) {
    int bc = blockIdx.x;
    const float* p = x + (size_t)bc * 3136;
    float s = 0.f;
    for (int i = threadIdx.x; i < 784; i += 256) {       // 784*4 = 3136
        f32x4 v = *(const f32x4*)(p + i * 4);
        s += v.x + v.y + v.z + v.w;
    }
#pragma unroll
    for (int off = 32; off; off >>= 1) s += __shfl_xor(s, off);
    __shared__ float red[4];
    int lane = threadIdx.x & 63, wave = threadIdx.x >> 6;
    if (lane == 0) red[wave] = s;
    __syncthreads();
    if (threadIdx.x == 0)
        pooled[bc] = (red[0] + red[1] + red[2] + red[3]) * (1.0f / 3136.0f);
}

// ---------------- Stage 2: h[b][i] = relu(sum_j pooled[b][j]*fc1_w[i][j]) ---
__global__ __launch_bounds__(256) void fc1_kernel(const float* __restrict__ pooled,
                                                  const float* __restrict__ w,
                                                  float* __restrict__ h) {
    __shared__ float pv[256];
    int b = blockIdx.x >> 6;
    pv[threadIdx.x] = pooled[b * 256 + threadIdx.x];
    __syncthreads();
    int lane = threadIdx.x & 63, wave = threadIdx.x >> 6;
    int i = ((blockIdx.x & 63) << 2) + wave;
    f32x4 v = *(const f32x4*)(w + i * 256 + lane * 4);
    float s = v.x * pv[lane * 4 + 0] + v.y * pv[lane * 4 + 1] +
              v.z * pv[lane * 4 + 2] + v.w * pv[lane * 4 + 3];
#pragma unroll
    for (int off = 32; off; off >>= 1) s += __shfl_xor(s, off);
    if (lane == 0) h[b * 256 + i] = fmaxf(s, 0.f);
}

// ---------------- Stage 3: kern[b][oc] = sum_j h[b][j]*fc2_w[oc][j] + b -----
__global__ __launch_bounds__(256) void fc2_kernel(const float* __restrict__ h,
                                                  const float* __restrict__ w,
                                                  const float* __restrict__ bias,
                                                  float* __restrict__ kern) {
    __shared__ float hv[256];
    int b = blockIdx.x >> 8;
    hv[threadIdx.x] = h[b * 256 + threadIdx.x];
    __syncthreads();
    int lane = threadIdx.x & 63, wave = threadIdx.x >> 6;
    int i = ((blockIdx.x & 255) << 2) + wave;
    f32x4 v = *(const f32x4*)(w + i * 256 + lane * 4);
    float s = v.x * hv[lane * 4 + 0] + v.y * hv[lane * 4 + 1] +
              v.z * hv[lane * 4 + 2] + v.w * hv[lane * 4 + 3];
#pragma unroll
    for (int off = 32; off; off >>= 1) s += __shfl_xor(s, off);
    if (lane == 0) kern[b * 1024 + i] = s + bias[i];
}

// ---------------- Stage 4: dynw[b][o][p][c] = bf16(sigmoid(cw)*weight) -----
// cw[b,o,c,p] = sum_t kern[b, c*4+t] * cog[o, t, p]
__global__ __launch_bounds__(256) void dynw_kernel(const float* __restrict__ kern,
                                                   const float* __restrict__ cogw,
                                                   const float* __restrict__ wgt,
                                                   u16* __restrict__ dynw) {
    __shared__ float wl[2304];                  // wgt[o][256 c][9 p]
    const int o = blockIdx.x & 255;
    const int bg = blockIdx.x >> 8;             // 0..3 -> 8 batches each
    const int c = threadIdx.x;
    const float* wo = wgt + (size_t)o * 2304;
#pragma unroll
    for (int j = 0; j < 9; ++j)                 // fully coalesced
        wl[j * 256 + c] = wo[j * 256 + c];
    __syncthreads();

    float cg0[9], cg1[9], cg2[9], cg3[9];       // cog[o][t][p] — wave-uniform
#pragma unroll
    for (int p = 0; p < 9; ++p) {
        cg0[p] = cogw[(o * 4 + 0) * 9 + p];
        cg1[p] = cogw[(o * 4 + 1) * 9 + p];
        cg2[p] = cogw[(o * 4 + 2) * 9 + p];
        cg3[p] = cogw[(o * 4 + 3) * 9 + p];
    }
    float w9[9];                                // stride-9 LDS read: odd -> conflict-free
#pragma unroll
    for (int p = 0; p < 9; ++p) w9[p] = wl[c * 9 + p];

    for (int b = bg * 8; b < bg * 8 + 8; ++b) {
        f32x4 k4 = *(const f32x4*)(kern + b * 1024 + c * 4);
        u16* dst = dynw + (size_t)(b * 256 + o) * 9 * 256 + c;
#pragma unroll
        for (int p = 0; p < 9; ++p) {
            float cw = k4.x * cg0[p] + k4.y * cg1[p] + k4.z * cg2[p] + k4.w * cg3[p];
            float sg = 1.0f / (1.0f + __expf(-cw));
            dst[p * 256] = f2bf(sg * w9[p]);    // coalesced per (b,p)
        }
    }
}

// ---------------- Stage 5: per-sample conv via implicit GEMM + MFMA --------
// v3: o-split for occupancy. Block tile: 128 o x 112 s (2 output rows);
// 4 waves; wave = 32 o x 112 s -> acc[2][7] = 56 regs (was 112).
// v1 loop structure byte-identical (stage -> sync -> compute -> sync),
// LDSW=40 layout unchanged. __launch_bounds__(256,3): cap ~170 regs/thread
// -> 3 blocks/CU (12 waves/CU) vs v1's 2 (8 waves). Cost: each x-tile is
// staged by 2 blocks (oh=0/1) -> x fetch doubles (HBM has 9x headroom).
// grid 1792 = 8 xcd-lanes * 4 b * 28 stile * 2 oh; adjacent slots = same
// stile, different oh -> x-tile L2-hot for the pair.
#define LDSW 40
__global__ __launch_bounds__(256, 3) void conv_kernel(const float* __restrict__ x,
                                                      const u16* __restrict__ dynw,
                                                      float* __restrict__ out) {
    __shared__ u16 lds[4 * 58 * LDSW];          // 18,560 B
    const int tid = threadIdx.x;
    const int wave = tid >> 6, lane = tid & 63;
    const int l15 = lane & 15, quad = lane >> 4;
    const int gid = blockIdx.x;
    const int slot = gid >> 3;                  // 0..223
    const int b = (gid & 7) * 4 + slot / 56;    // same-XCD blocks share b-slabs
    const int s2 = slot % 56;
    const int stile = s2 >> 1;                  // 0..27
    const int oh = s2 & 1;                      // o-half 0/1
    const int y0 = stile * 2;

    // zero halo columns xx=0 and xx=57 once (valid for every chunk), b64 writes
    if (tid < 64) {
        int side = tid & 1, yy = (tid >> 1) & 3, cg = tid >> 3;
        *(u16x4*)&lds[(yy * 58 + (side ? 57 : 0)) * LDSW + cg * 4] = (u16x4){0, 0, 0, 0};
    }

    f32x4 acc[2][7];
#pragma unroll
    for (int mf = 0; mf < 2; ++mf)
#pragma unroll
        for (int nf = 0; nf < 7; ++nf) acc[mf][nf] = (f32x4){0.f, 0.f, 0.f, 0.f};

    int bbase[7];
#pragma unroll
    for (int nf = 0; nf < 7; ++nf) {
        int n = nf * 16 + l15;                  // s within the 112-tile
        int r = (n >= 56) ? 1 : 0;
        int xx = n - 56 * r;
        bbase[nf] = (r * 58 + xx) * LDSW + quad * 8;
    }
    const u16* Abase = dynw + ((size_t)b * 256 + oh * 128 + wave * 32 + l15) * 2304 + quad * 8;
    const float* Xb = x + (size_t)b * 256 * 3136;

    __syncthreads();
    for (int cc = 0; cc < 8; ++cc) {
        // stage 32 c x 4 rows x 56 cols: 4 plane-strided loads -> one b64 write
#pragma unroll
        for (int it = 0; it < 7; ++it) {
            int i = it * 256 + tid;             // 1792 = 8 cg * 4 yy * 56 xx
            int q = i / 56;
            int xx = i - q * 56;
            int yy = q & 3;
            int cg = q >> 2;
            int yg = y0 - 1 + yy;
            u16x4 w = (u16x4){0, 0, 0, 0};
            if ((unsigned)yg < 56u) {
                const float* src = Xb + (size_t)(cc * 32 + cg * 4) * 3136 + yg * 56 + xx;
                w.x = f2bf(src[0]);
                w.y = f2bf(src[3136]);
                w.z = f2bf(src[2 * 3136]);
                w.w = f2bf(src[3 * 3136]);
            }
            *(u16x4*)&lds[(yy * 58 + 1 + xx) * LDSW + cg * 4] = w;   // 8B-aligned
        }
        __syncthreads();
#pragma unroll
        for (int p = 0; p < 9; ++p) {
            const int dy = p / 3, dx = p % 3;
            const int tapoff = (dy * 58 + dx) * LDSW;
            s16x8 a0 = *(const s16x8*)(Abase + 0 * 36864 + p * 256 + cc * 32);
            s16x8 a1 = *(const s16x8*)(Abase + 1 * 36864 + p * 256 + cc * 32);
#pragma unroll
            for (int nf = 0; nf < 7; ++nf) {
                s16x8 bf = *(const s16x8*)(&lds[bbase[nf] + tapoff]);
                acc[0][nf] = __builtin_amdgcn_mfma_f32_16x16x32_bf16(a0, bf, acc[0][nf], 0, 0, 0);
                acc[1][nf] = __builtin_amdgcn_mfma_f32_16x16x32_bf16(a1, bf, acc[1][nf], 0, 0, 0);
            }
        }
        __syncthreads();
    }
    // epilogue: D[row=quad*4+r][col=l15] (m89/m91-verified C/D layout)
#pragma unroll
    for (int mf = 0; mf < 2; ++mf) {
        int o = oh * 128 + wave * 32 + mf * 16 + quad * 4;
        size_t obase = ((size_t)b * 256 + o) * 3136 + (size_t)stile * 112 + l15;
#pragma unroll
        for (int nf = 0; nf < 7; ++nf) {
#pragma unroll
            for (int r = 0; r < 4; ++r)
                out[obase + (size_t)r * 3136 + nf * 16] = acc[mf][nf][r];
        }
    }
}

extern "C" void kernel_launch(void* const* d_in, const int* in_sizes, int n_in,
                              void* d_out, int out_size, void* d_ws, size_t ws_size,
                              hipStream_t stream) {
    const float* x    = (const float*)d_in[0];   // [32,256,56,56] f32
    const float* fc1w = (const float*)d_in[1];   // [256,256]
    const float* fc2w = (const float*)d_in[2];   // [1024,256]
    const float* fc2b = (const float*)d_in[3];   // [1024]
    const float* cogw = (const float*)d_in[4];   // [256,4,3,3]
    const float* wgt  = (const float*)d_in[5];   // [256,256,3,3]
    float* out = (float*)d_out;                  // [32,256,56,56] f32

    char* ws = (char*)d_ws;
    float* pooled = (float*)ws;              // 32 KB
    float* h      = (float*)(ws + 32768);    // 32 KB
    float* kern   = (float*)(ws + 65536);    // 128 KB
    u16*   dynw   = (u16*)(ws + 196608);     // 37.75 MB, [b][o][p][c] bf16

    pool_kernel<<<8192, 256, 0, stream>>>(x, pooled);
    fc1_kernel<<<2048, 256, 0, stream>>>(pooled, fc1w, h);
    fc2_kernel<<<8192, 256, 0, stream>>>(h, fc2w, fc2b, kern);
    dynw_kernel<<<1024, 256, 0, stream>>>(kern, cogw, wgt, dynw);
    conv_kernel<<<1792, 256, 0, stream>>>(x, dynw, out);
}